// Round 7
// baseline (141.907 us; speedup 1.0000x reference)
//
#include <hip/hip_runtime.h>
#include <hip/hip_bf16.h>

// DCNv2 forward: B=2, C=256, H=W=96, O=256, K=3x3, stride=1, pad=1, dil=1.
// Pipeline:
//  K1 prep     : (a) input NCHW fp32 -> NHWC bf16,
//                (b) weight -> bf16 stream order wt[kk][osub][cc][lane][8]
//  K2 dcn_main : per tap, cross-tap pipelined: issue next tap's corner loads,
//                run 16 MFMA chunks, do bilinear+LDS write spliced mid/post.
//
// R6 lesson: fill and compute alternated within each wave (MfmaUtil 15%,
// VALUBusy 23%, rest stall). Now: 64-s/256-O blocks (halves weight L2
// traffic), next-tap corner loads in flight across the whole compute phase,
// bilinear spliced at chunk 8 / post-loop into the other LDS buffer, one
// lgkm-only barrier per tap. LDS rows padded to 264 elems -> B-frag reads
// are base+imm (no per-chunk VALU); weight stream contiguous per wave.

#define Hh 96
#define Ww 96
#define Cc 256
#define Oo 256
#define Bb 2
#define Kk 9
#define Ss (Hh * Ww)          // 9216
#define CKTOT (Cc * Kk)       // 2304
#define ROWE 264              // LDS row stride in elems (528B, 16B-aligned)

typedef __bf16 bf16x8 __attribute__((ext_vector_type(8)));
typedef __bf16 bf16x2v __attribute__((ext_vector_type(2)));
typedef float f32x16 __attribute__((ext_vector_type(16)));
typedef float f32x2 __attribute__((ext_vector_type(2)));

__device__ __forceinline__ f32x2 up2(unsigned u) {
  f32x2 r;
  r.x = __uint_as_float(u << 16);
  r.y = __uint_as_float(u & 0xffff0000u);
  return r;
}

// barrier with LDS drain only — prefetched global loads stay in flight.
// simm16 0xC07F = lgkmcnt(0), expcnt(0), vmcnt(63)=no-wait.
__device__ __forceinline__ void barrier_lgkm() {
  asm volatile("" ::: "memory");
  __builtin_amdgcn_s_waitcnt(0xC07F);
  __builtin_amdgcn_s_barrier();
  asm volatile("" ::: "memory");
}

// ---------------- K1: merged prep ----------------
// blocks [0,1152)    : transpose NCHW fp32 -> NHWC bf16
// blocks [1152,3456) : weight repack to stream order:
//   wt[kk][osub][cc][lane][j]: o = osub*32 + (lane&31), ch = cc*16 + (lane>>5)*8 + j
__global__ __launch_bounds__(256) void prep(const float* __restrict__ inp,
                                            const float* __restrict__ wsrc,
                                            __bf16* __restrict__ it,
                                            __bf16* __restrict__ wt) {
  __shared__ float tile[64][65];
  const int bx = blockIdx.x;
  const int tid = threadIdx.x;

  if (bx < 1152) {
    const int hw0 = (bx % 144) * 64;
    const int c0 = ((bx / 144) & 3) * 64;
    const int b = bx / 576;
    const int hw_l = tid & 63, cr = tid >> 6;
    const float* src = inp + ((size_t)(b * Cc + c0) * Ss) + hw0;
#pragma unroll
    for (int r = 0; r < 16; ++r) {
      int c_l = r * 4 + cr;
      tile[c_l][hw_l] = src[(size_t)c_l * Ss + hw_l];
    }
    __syncthreads();
    const int cp = (tid & 31) * 2, hr = tid >> 5;
    __bf16* dst = it + ((size_t)(b * Ss + hw0) * Cc) + c0;
#pragma unroll
    for (int r = 0; r < 8; ++r) {
      int hw_s = r * 8 + hr;
      bf16x2v p;
      p.x = (__bf16)tile[cp][hw_s];
      p.y = (__bf16)tile[cp + 1][hw_s];
      *(bf16x2v*)(dst + (size_t)hw_s * Cc + cp) = p;
    }
  } else {
    int i = (bx - 1152) * 256 + tid;  // i < Oo*CKTOT = 589824
    int j = i & 7;
    int l = (i >> 3) & 63;
    int cc = (i >> 9) & 15;
    int osub = (i >> 13) & 7;
    int kk = i >> 16;
    int o = osub * 32 + (l & 31);
    int ch = cc * 16 + ((l >> 5) << 3) + j;
    wt[i] = (__bf16)wsrc[(o * Cc + ch) * Kk + kk];
  }
}

// ---------------- K2: fused sample + GEMM (cross-tap pipelined) ----------
// grid (144, 2): x = 64-s tile (XCD-swizzled), y = batch.
// 512 thr = 8 waves; wave wv: O-quarter ow=wv&3 (64 O), s-half sh=wv>>2 (32 s).
__global__ __launch_bounds__(512, 4) void dcn_main(
    const __bf16* __restrict__ it,     // [B][S][C] bf16
    const __bf16* __restrict__ wt,     // stream-order weights
    const float* __restrict__ offset,  // [B][18][S]
    const float* __restrict__ mask,    // [B][9][S]
    const float* __restrict__ bias,    // [O]
    float* __restrict__ out)           // [B][O][S]
{
  __shared__ __bf16 colT[2 * 64 * ROWE];  // dbuf tap tile [s:64][ch:256], padded rows
  __shared__ ushort4 pp[9][64];           // per-tap corner pixel indices
  __shared__ float4 pwl[9][64];           // per-tap corner weights (mask+valid folded)

  const int tid = threadIdx.x;
  // XCD swizzle: XCD j gets 18 contiguous 64-s tiles.
  const int tile = (blockIdx.x & 7) * 18 + (blockIdx.x >> 3);
  const int s0 = tile * 64;
  const int b = blockIdx.y;
  const int lane = tid & 63;
  const int wv = tid >> 6;
  const int ow = wv & 3;              // O quarter (64 O)
  const int sh = wv >> 2;             // s half (32 s)
  const int sB = lane & 31;
  const int hi = lane >> 5;
  const int srow = sh * 32 + sB;      // B-frag row in tile
  const int fs = tid >> 3;            // fill: s-row 0..63
  const int fg = tid & 7;             // fill: granule group 0..7

  const __bf16* itb = it + (size_t)b * Ss * Cc;

  // ---- bilinear params for all 9 taps up front ----
  for (int idx = tid; idx < 9 * 64; idx += 512) {
    int kk = idx >> 6;
    int sl = idx & 63;
    int s = s0 + sl;
    int ho = s / Ww;
    int wo = s - ho * Ww;
    float dy = offset[((size_t)(b * 18 + 2 * kk)) * Ss + s];
    float dx = offset[((size_t)(b * 18 + 2 * kk + 1)) * Ss + s];
    float m = mask[((size_t)(b * 9 + kk)) * Ss + s];
    float y = (float)(ho - 1 + kk / 3) + dy;
    float x = (float)(wo - 1 + kk % 3) + dx;
    float fy = floorf(y), fx = floorf(x);
    int y0 = (int)fy, x0 = (int)fx;
    float wy = y - fy, wx = x - fx;
    int y1 = y0 + 1, x1 = x0 + 1;
    float vy0 = (y0 >= 0 && y0 < Hh) ? 1.f : 0.f;
    float vy1 = (y1 >= 0 && y1 < Hh) ? 1.f : 0.f;
    float vx0 = (x0 >= 0 && x0 < Ww) ? 1.f : 0.f;
    float vx1 = (x1 >= 0 && x1 < Ww) ? 1.f : 0.f;
    int y0c = min(max(y0, 0), Hh - 1), y1c = min(max(y1, 0), Hh - 1);
    int x0c = min(max(x0, 0), Ww - 1), x1c = min(max(x1, 0), Ww - 1);
    pp[kk][sl] = make_ushort4((unsigned short)(y0c * Ww + x0c),
                              (unsigned short)(y0c * Ww + x1c),
                              (unsigned short)(y1c * Ww + x0c),
                              (unsigned short)(y1c * Ww + x1c));
    pwl[kk][sl] = make_float4(m * (1.f - wy) * (1.f - wx) * vy0 * vx0,
                              m * (1.f - wy) * wx * vy0 * vx1,
                              m * wy * (1.f - wx) * vy1 * vx0,
                              m * wy * wx * vy1 * vx1);
  }
  __syncthreads();

  f32x16 acc0, acc1;
#pragma unroll
  for (int j = 0; j < 16; ++j) { acc0[j] = 0.f; acc1[j] = 0.f; }

  // ---- fill-pipeline state ----
  unsigned ax0, ax1, ax2, ax3;  // corner byte offsets (pidx*512)
  float4 wq;
  uint4 D[2][4];                // 8 corner loads held (one half)

  auto tap_params = [&](int kk) {
    ushort4 q = pp[kk][fs];
    wq = pwl[kk][fs];
    ax0 = (unsigned)q.x << 9;
    ax1 = (unsigned)q.y << 9;
    ax2 = (unsigned)q.z << 9;
    ax3 = (unsigned)q.w << 9;
  };
  auto ld_half = [&](int half) {
    const char* base = (const char*)itb + fg * 16 + half * 256;
#pragma unroll
    for (int i2 = 0; i2 < 2; ++i2) {
      D[i2][0] = *(const uint4*)(base + ax0 + i2 * 128);
      D[i2][1] = *(const uint4*)(base + ax1 + i2 * 128);
      D[i2][2] = *(const uint4*)(base + ax2 + i2 * 128);
      D[i2][3] = *(const uint4*)(base + ax3 + i2 * 128);
    }
  };
  auto bil_half = [&](int tb, int half) {
    __bf16* drow = colT + tb * (64 * ROWE) + fs * ROWE + fg * 8 + half * 128;
#pragma unroll
    for (int i2 = 0; i2 < 2; ++i2) {
      unsigned u0[4] = {D[i2][0].x, D[i2][0].y, D[i2][0].z, D[i2][0].w};
      unsigned u1[4] = {D[i2][1].x, D[i2][1].y, D[i2][1].z, D[i2][1].w};
      unsigned u2[4] = {D[i2][2].x, D[i2][2].y, D[i2][2].z, D[i2][2].w};
      unsigned u3[4] = {D[i2][3].x, D[i2][3].y, D[i2][3].z, D[i2][3].w};
      bf16x8 rv;
#pragma unroll
      for (int w = 0; w < 4; ++w) {
        f32x2 r = up2(u0[w]) * wq.x + up2(u1[w]) * wq.y +
                  up2(u2[w]) * wq.z + up2(u3[w]) * wq.w;
        rv[2 * w] = (__bf16)r.x;
        rv[2 * w + 1] = (__bf16)r.y;
      }
      *(bf16x8*)(drow + i2 * 64) = rv;
    }
  };

  // weight stream bases for a tap (chunk cc at +cc*512 elems)
  auto wbaseA = [&](int kk) {
    return wt + (((size_t)kk * 8 + ow * 2) << 13) + lane * 8;
  };
  auto wbaseB = [&](int kk) {
    return wt + (((size_t)kk * 8 + ow * 2 + 1) << 13) + lane * 8;
  };

  // ---- prologue: fill tap 0 into buf 0 ----
  tap_params(0);
  ld_half(0);
  bil_half(0, 0);
  ld_half(1);
  bil_half(0, 1);
  bf16x8 WAc = *(const bf16x8*)wbaseA(0);
  bf16x8 WBc = *(const bf16x8*)wbaseB(0);

  for (int kk = 0; kk < 8; ++kk) {
    barrier_lgkm();
    const int buf = kk & 1;
    tap_params(kk + 1);
    ld_half(0);  // next tap's first 8 corner loads — in flight over compute

    const __bf16* rp = colT + buf * (64 * ROWE) + srow * ROWE + hi * 8;
    const __bf16* pA = wbaseA(kk);
    const __bf16* pB = wbaseB(kk);
    bf16x8 Bc = *(const bf16x8*)rp;
#pragma unroll
    for (int cc = 0; cc < 16; ++cc) {
      bf16x8 Bn, WAn, WBn;
      if (cc < 15) {
        Bn = *(const bf16x8*)(rp + (cc + 1) * 16);
        WAn = *(const bf16x8*)(pA + (cc + 1) * 512);
        WBn = *(const bf16x8*)(pB + (cc + 1) * 512);
      }
      acc0 = __builtin_amdgcn_mfma_f32_32x32x16_bf16(WAc, Bc, acc0, 0, 0, 0);
      acc1 = __builtin_amdgcn_mfma_f32_32x32x16_bf16(WBc, Bc, acc1, 0, 0, 0);
      if (cc == 7) {
        bil_half(buf ^ 1, 0);  // consume ld_half(0); write other buffer
        ld_half(1);
      }
      if (cc < 15) {
        Bc = Bn;
        WAc = WAn;
        WBc = WBn;
      }
    }
    bil_half(buf ^ 1, 1);
    WAc = *(const bf16x8*)wbaseA(kk + 1);  // next tap chunk-0, in flight over barrier
    WBc = *(const bf16x8*)wbaseB(kk + 1);
  }

  // ---- tail tap 8 (no fill) ----
  barrier_lgkm();
  {
    const __bf16* rp = colT + 0 * (64 * ROWE) + srow * ROWE + hi * 8;  // 8&1==0
    const __bf16* pA = wbaseA(8);
    const __bf16* pB = wbaseB(8);
    bf16x8 Bc = *(const bf16x8*)rp;
#pragma unroll
    for (int cc = 0; cc < 16; ++cc) {
      bf16x8 Bn, WAn, WBn;
      if (cc < 15) {
        Bn = *(const bf16x8*)(rp + (cc + 1) * 16);
        WAn = *(const bf16x8*)(pA + (cc + 1) * 512);
        WBn = *(const bf16x8*)(pB + (cc + 1) * 512);
      }
      acc0 = __builtin_amdgcn_mfma_f32_32x32x16_bf16(WAc, Bc, acc0, 0, 0, 0);
      acc1 = __builtin_amdgcn_mfma_f32_32x32x16_bf16(WBc, Bc, acc1, 0, 0, 0);
      if (cc < 15) {
        Bc = Bn;
        WAc = WAn;
        WBc = WBn;
      }
    }
  }

  // ---- epilogue: direct store with bias ----
  // D mapping (32x32): col(s)=sB, row(o-off)=(r&3)+8*(r>>2)+4*hi
  float* ob = out + (size_t)b * Oo * Ss + s0 + srow;
#pragma unroll
  for (int os = 0; os < 2; ++os) {
#pragma unroll
    for (int r = 0; r < 16; ++r) {
      int o = ow * 64 + os * 32 + (r & 3) + 8 * (r >> 2) + 4 * hi;
      float v = (os ? acc1[r] : acc0[r]) + bias[o];
      ob[(size_t)o * Ss] = v;
    }
  }
}

extern "C" void kernel_launch(void* const* d_in, const int* in_sizes, int n_in,
                              void* d_out, int out_size, void* d_ws, size_t ws_size,
                              hipStream_t stream) {
  (void)in_sizes; (void)n_in; (void)out_size; (void)ws_size;
  const float* inp = (const float*)d_in[0];
  const float* offset = (const float*)d_in[1];
  const float* mask = (const float*)d_in[2];
  const float* weight = (const float*)d_in[3];
  const float* bias = (const float*)d_in[4];
  float* out = (float*)d_out;

  __bf16* it = (__bf16*)d_ws;                                      // 9,437,184 B
  __bf16* wt = (__bf16*)((char*)d_ws + (size_t)Bb * Ss * Cc * 2);  // 1,179,648 B

  prep<<<3456, 256, 0, stream>>>(inp, weight, it, wt);
  dcn_main<<<dim3(144, Bb), 512, 0, stream>>>(it, wt, offset, mask, bias, out);
}